// Round 8
// baseline (688.675 us; speedup 1.0000x reference)
//
#include <hip/hip_runtime.h>
#include <math.h>

#define B   128
#define IN  64
#define HS  500
#define OUT 10

typedef float f4 __attribute__((ext_vector_type(4)));

#define NBLK1   (B * (HS / 4))     // 16000 blocks in kernel 1
#define HEBB_F4 (B * HS * HS / 4)  // 8,000,000 f4 total
#define COPY_PER_BLK (HEBB_F4 / NBLK1)  // 500 f4 per block

// ---------------------------------------------------------------------------
// Kernel 1: hactiv = tanh(i2h(x) + (w + alpha*pw) @ hidden)
//           + grid-striped hebb -> hebb_new copy (hides copy under the
//             latency-bound matvec; hebb copy depends on nothing).
// grid: B*(HS/4) = 16000 blocks, 256 threads (4 waves; 1 output row / wave)
// ---------------------------------------------------------------------------
__global__ __launch_bounds__(256)
void k_hactiv(const float* __restrict__ inputs,   // [B,IN]
              const float* __restrict__ hidden,   // [B,HS]
              const float* __restrict__ pw,       // [B,HS,HS]
              const float* __restrict__ i2h_w,    // [HS,IN]
              const float* __restrict__ i2h_b,    // [HS]
              const float* __restrict__ w,        // [HS,HS]
              const float* __restrict__ alpha,    // [HS,HS]
              const f4*    __restrict__ hebb,     // [B*HS*HS/4]
              f4*          __restrict__ hebb_new, // d_out slot, same shape
              float* __restrict__ hactiv,         // ws   [B,HS]
              float* __restrict__ hidden_new)     // d_out slot [B,HS]
{
    __shared__ f4 h_lds[HS / 4];                  // 125 vec4
    const int b    = blockIdx.x / (HS / 4);
    const int tile = blockIdx.x % (HS / 4);
    const int lane = threadIdx.x & 63;
    const int wv   = threadIdx.x >> 6;
    const int i    = tile * 4 + wv;

    if (threadIdx.x < HS / 4)
        h_lds[threadIdx.x] = ((const f4*)(hidden + (size_t)b * HS))[threadIdx.x];

    // ---- streamed hebb copy chunk (independent of everything else) ----
    {
        const size_t cbase = (size_t)blockIdx.x * COPY_PER_BLK;
        #pragma unroll
        for (int t = 0; t < COPY_PER_BLK / 256 + 1; ++t) {
            const int idx = t * 256 + threadIdx.x;
            if (idx < COPY_PER_BLK)
                hebb_new[cbase + idx] = hebb[cbase + idx];
        }
    }

    __syncthreads();

    const f4* __restrict__ pwrow = (const f4*)(pw + ((size_t)b * HS + i) * HS);
    const f4* __restrict__ wrow  = (const f4*)(w + (size_t)i * HS);
    const f4* __restrict__ arow  = (const f4*)(alpha + (size_t)i * HS);

    float acc = 0.f;
    #pragma unroll 2
    for (int v = lane; v < HS / 4; v += 64) {
        const f4 pv  = pwrow[v];
        const f4 wv4 = wrow[v];
        const f4 av  = arow[v];
        const f4 hv  = h_lds[v];
        acc += (wv4.x + av.x * pv.x) * hv.x
             + (wv4.y + av.y * pv.y) * hv.y
             + (wv4.z + av.z * pv.z) * hv.z
             + (wv4.w + av.w * pv.w) * hv.w;
    }

    // input projection: IN == 64, exactly one element per lane
    acc += inputs[b * IN + lane] * i2h_w[i * IN + lane];

    // wave64 shuffle reduce
    #pragma unroll
    for (int off = 32; off > 0; off >>= 1)
        acc += __shfl_down(acc, off, 64);

    if (lane == 0) {
        float v = tanhf(acc + i2h_b[i]);
        hactiv[b * HS + i]     = v;
        hidden_new[b * HS + i] = v;
    }
}

// ---------------------------------------------------------------------------
// Kernel 2: heads — activout [B,10], valueout [B,1], DAout [B] (tanh)
// grid: B blocks, 256 threads (4 waves × 3 outputs each = 12 outputs)
// ---------------------------------------------------------------------------
__global__ __launch_bounds__(256)
void k_heads(const float* __restrict__ hactiv,   // [B,HS]
             const float* __restrict__ h2o_w,    // [OUT,HS]
             const float* __restrict__ h2o_b,    // [OUT]
             const float* __restrict__ h2v_w,    // [1,HS]
             const float* __restrict__ h2v_b,    // [1]
             const float* __restrict__ h2DA_w,   // [1,HS]
             const float* __restrict__ h2DA_b,   // [1]
             float* __restrict__ activout,       // d_out [B,OUT]
             float* __restrict__ valueout,       // d_out [B]
             float* __restrict__ DAout)          // ws [B]
{
    __shared__ float h_lds[HS];
    const int b    = blockIdx.x;
    const int lane = threadIdx.x & 63;
    const int wv   = threadIdx.x >> 6;

    for (int j = threadIdx.x; j < HS; j += 256) h_lds[j] = hactiv[b * HS + j];
    __syncthreads();

    float acc[3] = {0.f, 0.f, 0.f};
    #pragma unroll
    for (int oo = 0; oo < 3; ++oo) {
        const int o = wv * 3 + oo;
        const float* __restrict__ wr =
            (o < OUT) ? (h2o_w + (size_t)o * HS) : ((o == OUT) ? h2v_w : h2DA_w);
        float a = 0.f;
        for (int j = lane; j < HS; j += 64) a += wr[j] * h_lds[j];
        acc[oo] = a;
    }
    #pragma unroll
    for (int off = 32; off > 0; off >>= 1) {
        #pragma unroll
        for (int oo = 0; oo < 3; ++oo)
            acc[oo] += __shfl_down(acc[oo], off, 64);
    }
    if (lane == 0) {
        #pragma unroll
        for (int oo = 0; oo < 3; ++oo) {
            const int o = wv * 3 + oo;
            if (o < OUT)          activout[b * OUT + o] = acc[oo] + h2o_b[o];
            else if (o == OUT)    valueout[b]           = acc[oo] + h2v_b[0];
            else                  DAout[b]              = tanhf(acc[oo] + h2DA_b[0]);
        }
    }
}

// ---------------------------------------------------------------------------
// Kernel 3: et/pw trace update over [B,HS,HS] — plain cached loads/stores
//   et_new = (1-etaet)*et + etaet * hactiv_i * hidden_j
//   pw_new = clip(pw + DAout_b * et, -1, 1)
// grid: (16, B) × 256 thr; each thread handles 2 consecutive f4 per iter
// (~7.6 iters; 6 independent 16B loads in flight per iteration).
// ---------------------------------------------------------------------------
#define NV4 (HS * HS / 4)   // 62500 f4 per batch
#define NP2 (NV4 / 2)       // 31250 f4-pairs per batch

__global__ __launch_bounds__(256)
void k_update(const f4* __restrict__ et,
              const f4* __restrict__ pw,
              const float* __restrict__ hactiv,   // [B,HS]
              const float* __restrict__ hidden,   // [B,HS] (old hidden)
              const float* __restrict__ DAout,    // [B]
              const float* __restrict__ etaet_p,  // [1]
              f4* __restrict__ et_new,
              f4* __restrict__ pw_new)
{
    const int   b     = blockIdx.y;
    const float etaet = etaet_p[0];
    const float omete = 1.f - etaet;
    const float da    = DAout[b];
    const size_t base = (size_t)b * NV4;

    const float* __restrict__ harow = hactiv + (size_t)b * HS;
    const f4*    __restrict__ hrow  = (const f4*)(hidden + (size_t)b * HS);

    const int stride = gridDim.x * blockDim.x;          // 16*256 = 4096
    for (int p2 = blockIdx.x * blockDim.x + threadIdx.x; p2 < NP2; p2 += stride) {
        const int v0 = 2 * p2;
        const int v1 = v0 + 1;
        const int i0 = v0 / (HS / 4);                   // magic-mul by 125
        const int j0 = v0 - i0 * (HS / 4);
        const int i1 = v1 / (HS / 4);
        const int j1 = v1 - i1 * (HS / 4);

        const f4 e0 = et[base + v0];
        const f4 e1 = et[base + v1];
        const f4 p0 = pw[base + v0];
        const f4 p1 = pw[base + v1];
        const float ha0 = harow[i0] * etaet;            // cache hit
        const float ha1 = harow[i1] * etaet;
        const f4 hj0 = hrow[j0];                        // cache hit
        const f4 hj1 = hrow[j1];

        f4 en0, en1, pn0, pn1;
        en0.x = omete * e0.x + ha0 * hj0.x;
        en0.y = omete * e0.y + ha0 * hj0.y;
        en0.z = omete * e0.z + ha0 * hj0.z;
        en0.w = omete * e0.w + ha0 * hj0.w;
        en1.x = omete * e1.x + ha1 * hj1.x;
        en1.y = omete * e1.y + ha1 * hj1.y;
        en1.z = omete * e1.z + ha1 * hj1.z;
        en1.w = omete * e1.w + ha1 * hj1.w;

        pn0.x = fminf(fmaxf(p0.x + da * e0.x, -1.f), 1.f);
        pn0.y = fminf(fmaxf(p0.y + da * e0.y, -1.f), 1.f);
        pn0.z = fminf(fmaxf(p0.z + da * e0.z, -1.f), 1.f);
        pn0.w = fminf(fmaxf(p0.w + da * e0.w, -1.f), 1.f);
        pn1.x = fminf(fmaxf(p1.x + da * e1.x, -1.f), 1.f);
        pn1.y = fminf(fmaxf(p1.y + da * e1.y, -1.f), 1.f);
        pn1.z = fminf(fmaxf(p1.z + da * e1.z, -1.f), 1.f);
        pn1.w = fminf(fmaxf(p1.w + da * e1.w, -1.f), 1.f);

        et_new[base + v0] = en0;
        et_new[base + v1] = en1;
        pw_new[base + v0] = pn0;
        pw_new[base + v1] = pn1;
    }
}

// ---------------------------------------------------------------------------
extern "C" void kernel_launch(void* const* d_in, const int* in_sizes, int n_in,
                              void* d_out, int out_size, void* d_ws, size_t ws_size,
                              hipStream_t stream) {
    const float* inputs  = (const float*)d_in[0];
    const float* hidden  = (const float*)d_in[1];
    const float* hebb    = (const float*)d_in[2];
    const float* et      = (const float*)d_in[3];
    const float* pw      = (const float*)d_in[4];
    const float* i2h_w   = (const float*)d_in[5];
    const float* i2h_b   = (const float*)d_in[6];
    const float* w       = (const float*)d_in[7];
    const float* alpha   = (const float*)d_in[8];
    // d_in[9] = eta (unused in fully_modulated path)
    const float* etaet   = (const float*)d_in[10];
    const float* h2DA_w  = (const float*)d_in[11];
    const float* h2DA_b  = (const float*)d_in[12];
    const float* h2o_w   = (const float*)d_in[13];
    const float* h2o_b   = (const float*)d_in[14];
    const float* h2v_w   = (const float*)d_in[15];
    const float* h2v_b   = (const float*)d_in[16];

    float* out = (float*)d_out;
    // d_out layout (floats): activout[1280] | valueout[128] | hidden_new[64000]
    //                        | hebb_new[32M] | et_new[32M] | pw_new[32M]
    float* activout   = out;
    float* valueout   = out + B * OUT;                       // 1280
    float* hidden_new = out + B * OUT + B;                   // 1408
    float* hebb_new   = out + B * OUT + B + B * HS;          // 65408 (16B-aligned)
    float* et_new     = hebb_new + (size_t)B * HS * HS;      // +32,000,000
    float* pw_new     = et_new + (size_t)B * HS * HS;

    float* hactiv = (float*)d_ws;            // [B*HS]
    float* DAout  = hactiv + B * HS;         // [B]

    // Phase 1: recurrent matvec + tanh, with hebb copy folded in
    k_hactiv<<<NBLK1, 256, 0, stream>>>(
        inputs, hidden, pw, i2h_w, i2h_b, w, alpha,
        (const f4*)hebb, (f4*)hebb_new, hactiv, hidden_new);

    // Phase 2: output heads + DA modulation
    k_heads<<<B, 256, 0, stream>>>(
        hactiv, h2o_w, h2o_b, h2v_w, h2v_b, h2DA_w, h2DA_b,
        activout, valueout, DAout);

    // Phase 3: et/pw streaming update, grid-stride per batch
    k_update<<<dim3(16, B), 256, 0, stream>>>(
        (const f4*)et, (const f4*)pw,
        hactiv, hidden, DAout, etaet,
        (f4*)et_new, (f4*)pw_new);
}